// Round 5
// baseline (659.292 us; speedup 1.0000x reference)
//
#include <hip/hip_runtime.h>

#define N_ 2000
#define L_ 1024

__device__ __forceinline__ float rcpf(float d) { return __builtin_amdgcn_rcpf(d); }
__device__ __forceinline__ float ex2(float x)  { return __builtin_amdgcn_exp2f(x); }

// lane <-> lane^1 exchange via DPP quad_perm:[1,0,3,2] -- VALU latency only.
__device__ __forceinline__ float dppx1(float x) {
    return __int_as_float(
        __builtin_amdgcn_mov_dpp(__float_as_int(x), 0xB1, 0xF, 0xF, true));
}

// Pair-split step (R1 structure, best measured density), parameterized by
// chain state so each lane can run TWO independent chains whose instruction
// streams interleave in the static schedule (fills in-order dependency stalls).
// even lane = M-rates + gates (m,h); odd = N-rates + gates (n,y).
#define STEP2(V, sA, sB, eRp, zb, basev, K, RS, DOSTORE)                      \
  {                                                                           \
    const int kk = (K);                                                       \
    float zc = zb[RS];                                                        \
    int kpre = kk + 7;                                                        \
    int kc = kpre < 1998 ? kpre : 1998;                                       \
    zb[RS] = z[basev + kc * L_];                                              \
    /* Vn partials: val = m^3*h (even) | n^4 (odd) */                         \
    float w    = evn ? sB : sA;                                               \
    float t1   = sA * sA;                                                     \
    float val  = (t1 * sA) * w;                                               \
    float gAdd = evn ? 0.003f : 0.01f * sB;   /* GL*DT2 | DT2*y */            \
    float Gh   = __fmaf_rn(val, cG, gAdd);                                    \
    float Eh   = __fmaf_rn(val, cE, eAdd);                                    \
    float G    = Gh + dppx1(Gh);                                              \
    float E    = Eh + dppx1(Eh);                                              \
    float num  = __fmaf_rn(V, 1.0f - G, __fmaf_rn(E, 0.02f, 0.02f));          \
    float Vn   = num * rcpf(1.0f + G);                                        \
    /* rates: eR = exp((Vn+35)/9) (even) | exp((Vn-25)/9) (odd), direct */    \
    float eR   = ex2(__fmaf_rn(Vn, K9, cX));                                  \
    float u    = Vn + cu;                                                     \
    float r    = rcpf(eR - 1.0f);                                             \
    float ur   = u * r;                                                       \
    bool  pat  = (Vn == cc);                                                  \
    float av   = pat ? pa  : ka * (ur * eR);                                  \
    float s1   = pat ? cs1 : ur * __fmaf_rn(ka01, eR, kb01);                  \
    /* H-exps: even computes aH, odd computes bH; swap bH to even via DPP */  \
    float vH   = 0.25f * ex2(__fmaf_rn(Vn, sHc, cHc));                        \
    float vHx  = dppx1(vH);                                                   \
    /* gate slot 1: m (even) | n (odd) */                                     \
    float q1   = 1.0f + s1;                                                   \
    float num1 = __fmaf_rn(av, 0.02f, __fmaf_rn(-s1, sA, sA));                \
    /* gate slot 2: h (even) | y (odd) */                                     \
    float a2   = evn ? vH  : zc;                                              \
    float b2   = evn ? vHx : 0.1f;                                            \
    float s2   = __fmaf_rn(a2, 0.01f, 0.01f * b2);                            \
    float q2   = 1.0f + s2;                                                   \
    float num2 = __fmaf_rn(a2, 0.02f, __fmaf_rn(-s2, sB, sB));                \
    float rq   = rcpf(q1 * q2);                                               \
    sA = num1 * (rq * q2);                                                    \
    sB = num2 * (rq * q1);                                                    \
    V = Vn;                                                                   \
    if (DOSTORE) {                                                            \
      /* lanes split output rows K-1 (even, via eRp) and K (odd, via eR) */   \
      float esel = evn ? eRp : eR;                                            \
      float e3 = (esel * esel) * esel;                                        \
      float ts = e3 * C15L;              /* = exp((V+20)/3) */                \
      float sg = ts * rcpf(1.0f + ts);                                        \
      out[basev + (kk - 1 + sub) * L_] = sg;                                  \
    } else {                                                                  \
      eRp = eR;                                                               \
    }                                                                         \
  }

__global__ __launch_bounds__(64) void hh_kernel(const float* __restrict__ z,
                                                float* __restrict__ out) {
    const int t   = blockIdx.x * 64 + threadIdx.x;   // 0 .. 16383
    const int sub = t & 1;
    const int ch  = t >> 1;                           // pair 0..8191 = chain A
    const int b   = ch >> 10;                         // 0..7
    const int l   = ch & 1023;
    const int baseA = b * (N_ * L_) + l;              // chain A: b   in 0..7
    const int baseB = baseA + 8 * (N_ * L_);          // chain B: b+8 in 8..15

    const bool evn = (sub == 0);

    const float K9  = 0.16029944898766259f;   // log2(e)/9
    const float K12 = 0.12022458674074695f;   // log2(e)/12

    // per-lane constants (shared by both chains)
    const float cG   = evn ? 0.4f      : 0.35f;     // DT2*GNA | DT2*GK
    const float cE   = evn ? 2200.0f   : -2695.0f;  // GNA*ENA | GK*EK
    const float eAdd = evn ? -19.5f    : 0.0f;      // GL*EL   | 0
    const float cu   = evn ? 35.0f     : -25.0f;    // u = Vn + cu
    const float cX   = evn ? 35.0f*K9  : -25.0f*K9; // eR = exp2(Vn*K9 + cX)
    const float cc   = evn ? -35.0f    : 25.0f;     // singularity compare
    const float ka   = evn ? 0.182f    : 0.02f;
    const float ka01 = evn ? 0.00182f  : 0.0002f;   // 0.01*ka
    const float kb01 = evn ? 0.00124f  : 0.00002f;  // 0.01*kb
    const float pa   = evn ? 1.638f    : 0.18f;     // patched a
    const float cs1  = evn ? 0.02798f  : 0.0026f;   // 0.01*(pa+pb)
    const float sHc  = evn ? -K12      : K12;       // argH = sHc*Vn + cHc
    const float cHc  = evn ? -90.0f*K12 : 34.0f*K12;
    const float C15L = evn ? 0.006737946999085467f  // e^-5 (corrects eR_even^3)
                           : 3269017.372472110639f; // e^15

    // chain A state
    float VA  = -70.0f;
    float sAA = 0.0f;
    float sBA = evn ? 1.0f : 0.0f;
    float eRpA = ex2((-70.0f + 35.0f) * K9);
    // chain B state
    float VB  = -70.0f;
    float sAB = 0.0f;
    float sBB = evn ? 1.0f : 0.0f;
    float eRpB = ex2((-70.0f + 35.0f) * K9);

    float zbA[8], zbB[8];
#pragma unroll
    for (int i = 0; i < 8; ++i) zbA[i] = z[baseA + i * L_];
#pragma unroll
    for (int i = 0; i < 8; ++i) zbB[i] = z[baseB + i * L_];

    // pair-steps: odd K stores rows (K-1, K); even K saves eRp.
    int k2 = 1;
    for (int g = 0; g < 249; ++g) {          // K = 1 .. 1992
#pragma unroll
        for (int j = 0; j < 4; ++j) {
            STEP2(VA, sAA, sBA, eRpA, zbA, baseA, k2 + 2 * j,     2 * j,     true)
            STEP2(VB, sAB, sBB, eRpB, zbB, baseB, k2 + 2 * j,     2 * j,     true)
            STEP2(VA, sAA, sBA, eRpA, zbA, baseA, k2 + 2 * j + 1, 2 * j + 1, false)
            STEP2(VB, sAB, sBB, eRpB, zbB, baseB, k2 + 2 * j + 1, 2 * j + 1, false)
        }
        k2 += 8;
    }
    // k2 == 1993: remaining pairs K=1993..1998, then K=1999
#pragma unroll
    for (int j = 0; j < 3; ++j) {
        STEP2(VA, sAA, sBA, eRpA, zbA, baseA, k2 + 2 * j,     2 * j,     true)
        STEP2(VB, sAB, sBB, eRpB, zbB, baseB, k2 + 2 * j,     2 * j,     true)
        STEP2(VA, sAA, sBA, eRpA, zbA, baseA, k2 + 2 * j + 1, 2 * j + 1, false)
        STEP2(VB, sAB, sBB, eRpB, zbB, baseB, k2 + 2 * j + 1, 2 * j + 1, false)
    }
    STEP2(VA, sAA, sBA, eRpA, zbA, baseA, 1999, 6, true)
    STEP2(VB, sAB, sBB, eRpB, zbB, baseB, 1999, 6, true)
}

extern "C" void kernel_launch(void* const* d_in, const int* in_sizes, int n_in,
                              void* d_out, int out_size, void* d_ws, size_t ws_size,
                              hipStream_t stream) {
    const float* z = (const float*)d_in[0];
    float* out = (float*)d_out;
    // 8192 pairs x 2 lanes x 2 chains/lane = 16384 threads = 256 waves (1 per CU)
    hh_kernel<<<256, 64, 0, stream>>>(z, out);
}

// Round 6
// 495.374 us; speedup vs baseline: 1.3309x; 1.3309x over previous
//
#include <hip/hip_runtime.h>

#define N_ 2000
#define L_ 1024

__device__ __forceinline__ float rcpf(float d) { return __builtin_amdgcn_rcpf(d); }
__device__ __forceinline__ float ex2(float x)  { return __builtin_amdgcn_exp2f(x); }

// Trans-minimized full-chain step: 3 ex2 + 3 rcp per step (prev best: 4 ex2 + 6 rcp).
//  - eRn = eRm * e^{-60/9}   (constant-ratio exponentials)
//  - rrm,rrn share one rcp((eRm-1)(eRn-1)), singularity-guarded
//  - all 4 gate denominators + output sigmoid share one rcp
// Ring-8 z prefetch: step K consumes z[K-1] (slot (K-1)&7), prefetches z[K+7].
#define STEP1(K, RS)                                                          \
  {                                                                           \
    const int kk = (K);                                                       \
    float zc = zb[RS];                                                        \
    int kpre = kk + 7;                                                        \
    int kc = kpre < 1998 ? kpre : 1998;                                       \
    zb[RS] = z[base + kc * L_];                                               \
    /* conductance trees */                                                   \
    float mh   = m * h;                                                       \
    float m2   = m * m;                                                       \
    float valm = m2 * mh;              /* m^3 h */                            \
    float n2   = n * n;                                                       \
    float valn = n2 * n2;              /* n^4  */                            \
    float gy   = __fmaf_rn(y, 0.01f, 0.003f);                                 \
    float G    = __fmaf_rn(valm, 0.4f, __fmaf_rn(valn, 0.35f, gy));           \
    float E    = __fmaf_rn(valm, 2200.0f, __fmaf_rn(valn, -2695.0f, -19.5f)); \
    float rV   = rcpf(1.0f + G);                                              \
    float tVD  = __fmaf_rn(E, 0.02f, __fmaf_rn(2.0f, V, 0.02f));              \
    float Vn   = __fmaf_rn(tVD, rV, -V);     /* (2V+DT(E+1))/(1+G) - V */     \
    /* m,n rates: one ex2, one shared rcp */                                  \
    float eRm  = ex2(__fmaf_rn(Vn, K9, 35.0f * K9));   /* e^{(Vn+35)/9} */    \
    float eRn  = eRm * CN;                             /* e^{(Vn-25)/9} */    \
    float dm   = eRm - 1.0f;                                                  \
    float dn   = eRn - 1.0f;                                                  \
    bool patm  = (Vn == -35.0f);                                              \
    bool patn  = (Vn == 25.0f);                                               \
    float dmS  = patm ? 1.0f : dm;      /* guard: zero denom can't poison */  \
    float dnS  = patn ? 1.0f : dn;      /* the other gate via the pairing */  \
    float rp   = rcpf(dmS * dnS);                                             \
    float rrm  = rp * dnS;                                                    \
    float rrn  = rp * dmS;                                                    \
    float um   = Vn + 35.0f;                                                  \
    float un   = Vn - 25.0f;                                                  \
    float urm  = um * rrm;                                                    \
    float urn  = un * rrn;                                                    \
    float sm   = urm * __fmaf_rn(0.00182f, eRm, 0.00124f);                    \
    float sn   = urn * __fmaf_rn(0.0002f,  eRn, 0.00002f);                    \
    float aM   = 0.182f * (urm * eRm);                                        \
    float aN   = 0.02f  * (urn * eRn);                                        \
    sm = patm ? 0.02798f : sm;  aM = patm ? 1.638f : aM;                      \
    sn = patn ? 0.0026f  : sn;  aN = patn ? 0.18f  : aN;                      \
    /* H rates (2 ex2, off critical path) */                                  \
    float aH   = 0.25f * ex2(__fmaf_rn(Vn, -K12, -90.0f * K12));              \
    float bH   = 0.25f * ex2(__fmaf_rn(Vn,  K12,  34.0f * K12));              \
    float sh   = __fmaf_rn(aH, 0.01f, 0.01f * bH);                            \
    float sy   = __fmaf_rn(zc, 0.01f, 0.001f);                                \
    float qm = 1.0f + sm, qn = 1.0f + sn, qh = 1.0f + sh, qy = 1.0f + sy;     \
    float numm = __fmaf_rn(aM, 0.02f, __fmaf_rn(-sm, m, m));                  \
    float numn = __fmaf_rn(aN, 0.02f, __fmaf_rn(-sn, n, n));                  \
    float numh = __fmaf_rn(aH, 0.02f, __fmaf_rn(-sh, h, h));                  \
    float numy = __fmaf_rn(zc, 0.02f, __fmaf_rn(-sy, y, y));                  \
    /* output sigmoid arg: t = eRm^3 e^-5 = e^{(Vn+20)/3} (no extra ex2) */   \
    float e2 = eRm * eRm;                                                     \
    float ts = (e2 * eRm) * 0.006737946999085467f;                            \
    float uS = 1.0f + ts;                                                     \
    /* one rcp serves 4 gate denoms + sigmoid */                              \
    float t1 = qm * qn;                                                       \
    float t2 = qh * qy;                                                       \
    float t12 = t1 * t2;                                                      \
    float rall = rcpf(t12 * uS);                                              \
    float rq  = rall * uS;      /* 1/(t1 t2) */                               \
    float rs  = rall * t12;     /* 1/(1+ts)  */                               \
    float rmn = rq * t2;        /* 1/(qm qn) */                               \
    float rhy = rq * t1;        /* 1/(qh qy) */                               \
    m = numm * (rmn * qn);                                                    \
    n = numn * (rmn * qm);                                                    \
    h = numh * (rhy * qy);                                                    \
    y = numy * (rhy * qh);                                                    \
    V = Vn;                                                                   \
    float sg = ts * rs;                                                       \
    out[base + kk * L_] = sg;                                                 \
  }

__global__ __launch_bounds__(64) void hh_kernel(const float* __restrict__ z,
                                                float* __restrict__ out) {
    const int t   = blockIdx.x * 64 + threadIdx.x;   // chain 0..16383
    const int b   = t >> 10;
    const int l   = t & 1023;
    const int base = b * (N_ * L_) + l;

    const float K9  = 0.16029944898766259f;   // log2(e)/9
    const float K12 = 0.12022458674074695f;   // log2(e)/12
    const float CN  = 0.0012726338013398079f; // e^{-60/9}: eRn = eRm * CN

    float V = -70.0f;
    float m = 0.0f, n = 0.0f, h = 1.0f, y = 0.0f;

    float zb[8];
#pragma unroll
    for (int i = 0; i < 8; ++i) zb[i] = z[base + i * L_];

    // row 0: sigmoid((-70+20)/3), constant
    out[base] = 5.777750e-8f;

    int k = 1;
    for (int g = 0; g < 249; ++g) {          // K = 1 .. 1992
#pragma unroll
        for (int j = 0; j < 8; ++j) {
            STEP1(k + j, j)
        }
        k += 8;
    }
    // K = 1993 .. 1999 (slots 0..6)
#pragma unroll
    for (int j = 0; j < 7; ++j) {
        STEP1(k + j, j)
    }
}

extern "C" void kernel_launch(void* const* d_in, const int* in_sizes, int n_in,
                              void* d_out, int out_size, void* d_ws, size_t ws_size,
                              hipStream_t stream) {
    const float* z = (const float*)d_in[0];
    float* out = (float*)d_out;
    // 16384 chains x 1 lane = 16384 threads = 256 waves (1 per CU)
    hh_kernel<<<256, 64, 0, stream>>>(z, out);
}